// Round 11
// baseline (266.817 us; speedup 1.0000x reference)
//
#include <hip/hip_runtime.h>
#include <math.h>

#define EPSV 1e-10f

typedef _Float16 f16x8 __attribute__((ext_vector_type(8)));
typedef _Float16 f16x4 __attribute__((ext_vector_type(4)));
typedef float f32x4 __attribute__((ext_vector_type(4)));

// ---------------- agg LDS layout (bytes), R17 ----------------
// A (0..16384):     prologue W1T f16 [64][128] swz (8KB used)
//                   -> main loop: 4 wave-private DOUBLE H slots (wave*4096,
//                      two 2048B halves, parity = tile idx & 1)
// B (16384..24576): W2T[n2][h] f16 swz (P2a -> end)
// C (24576..32768): M2T[n3][h] f16 swz (P2b -> end)
// AU f32 [64][64] = 16KB overlays B+C during P0/P1 (dead before W2T staged).
// D (32768..36864): uS f32 16x64 (P0/P1); then cstP(1K)+sB1(256B)+sR1(1.7K)
// E (36864..40960): sV[g][n], g < 16
// LDS 40960 (4 blocks/CU) is free: R16 proved 32K vs 40K occupancy-identical
// (registers bind at 4 waves/SIMD).
#define OFF_W1T  0
#define OFF_AU   16384
#define OFF_W2T  16384
#define OFF_M2T  24576
#define OFF_U    32768
#define OFF_B1   33792
#define OFF_R1   34048
#define OFF_V    36864
#define SMEM_SZ  40960

__device__ __forceinline__ f16x8 cvt_f16x8(const float4 a, const float4 b) {
  f16x8 h;
  h[0] = (_Float16)a.x; h[1] = (_Float16)a.y; h[2] = (_Float16)a.z; h[3] = (_Float16)a.w;
  h[4] = (_Float16)b.x; h[5] = (_Float16)b.y; h[6] = (_Float16)b.z; h[7] = (_Float16)b.w;
  return h;
}

// ---------------------------------------------------------------------------
// Fused item-aggregation. I-blocks FIRST [0,nIblk): 4 groups (P=100, 1/wave);
// S-blocks after: 16 groups (P=40, 4/wave). 256 thr = 4 waves.
// R17: two-tile software pipeline. R16 closed the occupancy lever (registers
// bind at 4 waves/SIMD; LDS headroom is free). The wall is the per-tile
// serial chain (L1 MFMA -> H LDS write -> read -> d-MFMA -> softmax ->
// c-MFMA), ~56% SIMD-idle. Split each tile into stage1 (L1+H-write) and
// stage2 (H-read..pnum/flush) and run s1(t+1), s2(t), s1(t+2), s2(t+1):
// a full stage of independent MFMA+VALU sits between every H write and its
// dependent read. H slots double-buffered (parity compile-time in the
// 2-unrolled loop); +2 live VGPR; no math changes.
// Tripwires: FETCH ~101MB / WRITE ~5.2MB / VGPR ~80-90.
// ---------------------------------------------------------------------------
__global__ __launch_bounds__(256, 3) void agg_kernel(
    const int nIblk,
    const int* __restrict__ idsS, const int* __restrict__ uidS,
    const int* __restrict__ idsI, const int* __restrict__ uidI,
    const float* __restrict__ user_table, const float* __restrict__ item_table,
    const float* __restrict__ rate_table,
    const float* __restrict__ gv_W1, const float* __restrict__ gv_b1,
    const float* __restrict__ gv_W2, const float* __restrict__ gv_b2,
    const float* __restrict__ atti_W1, const float* __restrict__ atti_b1,
    const float* __restrict__ atti_W2, const float* __restrict__ atti_b2,
    const float* __restrict__ agg_W, const float* __restrict__ agg_b,
    float* __restrict__ outS, float* __restrict__ outI) {
  __shared__ __align__(16) char smem[SMEM_SZ];
  const int tid = threadIdx.x;
  const int wave = tid >> 6, lane = tid & 63;
  const int quad = lane >> 4, mrow = lane & 15;

  const bool isS = (int)blockIdx.x >= nIblk;
  const int NG = isS ? 16 : 4;
  const int P = isS ? 40 : 100;
  const int nGrp = isS ? 4 : 1;  // groups per wave
  const int tpg = isS ? 3 : 8;   // 16-row tiles per group
  const int nIdx = nGrp * tpg;   // 12 or 8 (both even)
  const int* __restrict__ ids = isS ? idsS : idsI;
  const int* __restrict__ uidp = isS ? uidS : uidI;
  float* __restrict__ out = isS ? outS : outI;
  const int gbase = isS ? ((int)blockIdx.x - nIblk) * 16 : (int)blockIdx.x * 4;

  float* sV = (float*)(smem + OFF_V);
  char* smXw = smem + wave * 4096;  // wave-private double H slot (post-B5)

  // ---- P0: uS (region D) + AU = AW1u^T f32 (overlay on B+C, f4-swizzled) ----
  {
    float* uS = (float*)(smem + OFF_U);
    float* AU = (float*)(smem + OFF_AU);
    for (int t = tid; t < NG * 64; t += 256) {
      const int g = t >> 6, f = t & 63;
      uS[t] = user_table[(size_t)uidp[gbase + g] * 64 + f];
    }
    for (int o = tid; o < 1024; o += 256) {  // AU[j][k] = atti_W1[64+k][j]
      const int k = o >> 4, fb = o & 15;
      const float4 v = ((const float4*)(atti_W1 + (64 + k) * 64))[fb];
      const float* vp = (const float*)&v;
#pragma unroll
      for (int c = 0; c < 4; ++c) {
        const int j = fb * 4 + c;
        AU[j * 64 + (((k >> 2) ^ (j & 15)) << 2) + (k & 3)] = vp[c];
      }
    }
  }
  __syncthreads();
  // ---- P1: v[g][j] = u[g] . AW1u[:,j] ----
  {
    const float4* u4 = (const float4*)(smem + OFF_U);
    const float4* a4 = (const float4*)(smem + OFF_AU);
    for (int t = tid; t < NG * 64; t += 256) {
      const int g = t >> 6, j = t & 63;
      float s = 0.f;
#pragma unroll 4
      for (int kb = 0; kb < 16; ++kb) {
        const float4 uu = u4[g * 16 + kb];
        const float4 aa = a4[j * 16 + (kb ^ (j & 15))];
        s += uu.x * aa.x + uu.y * aa.y + uu.z * aa.z + uu.w * aa.w;
      }
      sV[t] = s;
    }
  }
  __syncthreads();  // AU dead beyond this point (B/C regions reusable)
  // ---- P2a: W1T(item)/W2T f16 staging + R1 f32 + b1 bank + cst partials ----
  {
    for (int o = tid; o < 1024; o += 256) {  // W1T[n][k], k in 0..63 (item)
      const int k = o >> 4, fb = o & 15;
      const float4 v = ((const float4*)(gv_W1 + k * 64))[fb];
      const float* vp = (const float*)&v;
#pragma unroll
      for (int c = 0; c < 4; ++c) {
        const int n = fb * 4 + c;
        *(_Float16*)(smem + OFF_W1T + n * 128 + ((((k >> 3) ^ (n & 7))) << 4) +
                     ((k & 7) << 1)) = (_Float16)vp[c];
      }
    }
    for (int o = tid; o < 1024; o += 256) {  // W2T[n2][h]
      const int h = o >> 4, fb = o & 15;
      const float4 v = ((const float4*)(gv_W2 + h * 64))[fb];
      const float* vp = (const float*)&v;
#pragma unroll
      for (int c = 0; c < 4; ++c) {
        const int n = fb * 4 + c;
        *(_Float16*)(smem + OFF_W2T + n * 128 + ((((h >> 3) ^ (n & 7))) << 4) +
                     ((h & 7) << 1)) = (_Float16)vp[c];
      }
    }
    // sR1 f32: R1[r][n] = rate_r . W1[64:,n], pitch 68 floats (bank-spread)
    {
      float* sR1 = (float*)(smem + OFF_R1);
      for (int o = tid; o < 384; o += 256) {
        const int r = o >> 6, n = o & 63;
        float s = 0.f;
#pragma unroll 8
        for (int k = 0; k < 64; ++k)
          s = fmaf(rate_table[r * 64 + k], gv_W1[(64 + k) * 64 + n], s);
        sR1[r * 68 + n] = s;
      }
    }
    // sB1: gv_b1 bank (live through the main loop)
    if (tid < 16) ((float4*)(smem + OFF_B1))[tid] = ((const float4*)gv_b1)[tid];
    float* sCstP = (float*)(smem + OFF_U);  // uS dead after P1
    const int n = tid & 63, jh = tid >> 6;
    float p = 0.f;
#pragma unroll 4
    for (int jj = 0; jj < 16; ++jj) {
      const int j = jh * 16 + jj;
      p = fmaf(gv_b2[j], atti_W1[j * 64 + n], p);
    }
    sCstP[jh * 64 + n] = p;
  }
  // per-lane constant preloads (global, L2-hot)
  float b2v[4], aw2v[4];
#pragma unroll
  for (int nt = 0; nt < 4; ++nt) {
    b2v[nt] = gv_b2[nt * 16 + mrow];
    aw2v[nt] = atti_W2[nt * 16 + mrow];
  }
  const float ab2 = atti_b2[0];

  // ---- single-buffer split prefetch (1 tile lookahead) ----
  const int nIdxM1 = nIdx - 1;
  int2 idreg;
  float4 pf[4];
  float pm;
  int rid;
  auto load_ids = [&](int idx) __attribute__((always_inline)) {
    const int ic = idx < nIdxM1 ? idx : nIdxM1;  // clamp (tail prefetch harmless)
    const int gq = isS ? (ic * 11) >> 5 : (ic >> 3);  // /3 or /8, ic<=11
    const int tt = ic - gq * tpg;
    const int it = tt * 16 + mrow;
    int2 pr = make_int2(0, 0);
    if (it < P) {
      const int g2 = gbase + wave + 4 * gq;
      pr = ((const int2*)ids)[(size_t)g2 * P + it];
    }
    idreg = pr;
  };
  auto issue_gather = [&]() __attribute__((always_inline)) {
    const int iid = idreg.x;
    rid = idreg.y;
    pm = iid > 0 ? 1.f : 0.f;
    const float* ib = item_table + (size_t)iid * 64 + quad * 8;
    pf[0] = ((const float4*)ib)[0];
    pf[1] = ((const float4*)ib)[1];
    pf[2] = ((const float4*)(ib + 32))[0];
    pf[3] = ((const float4*)(ib + 32))[1];
  };
  load_ids(0); issue_gather();
  load_ids(1);      // in flight across P2b
  __syncthreads();  // B3: W1T/W2T/cstP/sB1/sR1 ready
  // ---- P2b: M2T via MFMA (A,B from L2-hot global) + cstv to registers ----
  float cstv[4];
  {
    f16x8 aM[2];
#pragma unroll
    for (int ks = 0; ks < 2; ++ks) {
      f16x8 t;
#pragma unroll
      for (int j = 0; j < 8; ++j)
        t[j] = (_Float16)atti_W1[(ks * 32 + quad * 8 + j) * 64 + (wave * 16 + mrow)];
      aM[ks] = t;
    }
#pragma unroll
    for (int ht = 0; ht < 4; ++ht) {
      f32x4 c = {0.f, 0.f, 0.f, 0.f};
#pragma unroll
      for (int ks = 0; ks < 2; ++ks) {
        const float* s = gv_W2 + (ht * 16 + mrow) * 64 + ks * 32 + quad * 8;
        f16x8 b;
#pragma unroll
        for (int j = 0; j < 8; ++j) b[j] = (_Float16)s[j];
        c = __builtin_amdgcn_mfma_f32_16x16x32_f16(aM[ks], b, c, 0, 0, 0);
      }
      const int h = ht * 16 + mrow;
#pragma unroll
      for (int rg = 0; rg < 4; ++rg) {
        const int n3 = wave * 16 + quad * 4 + rg;
        *(_Float16*)(smem + OFF_M2T + n3 * 128 + ((((h >> 3) ^ (n3 & 7))) << 4) +
                     ((h & 7) << 1)) = (_Float16)c[rg];
      }
    }
    const float* sCstP = (const float*)(smem + OFF_U);
#pragma unroll
    for (int nt = 0; nt < 4; ++nt) {
      const int n = nt * 16 + mrow;
      cstv[nt] = atti_b1[n] + sCstP[n] + sCstP[64 + n] + sCstP[128 + n] +
                 sCstP[192 + n];
    }
  }
  __syncthreads();  // B4: M2T ready

  // ---- hoist W1 A-frags (item k-halves only) into registers ----
  f16x8 aW[4][2];
#pragma unroll
  for (int nt = 0; nt < 4; ++nt) {
#pragma unroll
    for (int ks = 0; ks < 2; ++ks)
      aW[nt][ks] = *(const f16x8*)(smem + OFF_W1T + (nt * 16 + mrow) * 128 +
                                   (((ks * 4 + quad) ^ (mrow & 7)) << 4));
  }
  __syncthreads();  // B5: hoist done; region A becomes per-wave double H slots

  // =================== pipelined barrier-free main loop ===================
  const float* sR1 = (const float*)(smem + OFF_R1);
  float vv[4], pnum[4], pden = 0.f;

  // stage1(t): cvt + L1 MFMA + biases -> H write to slot (par)
  auto stage1 = [&](const int par, float& mS) __attribute__((always_inline)) {
    f16x8 bIn0 = cvt_f16x8(pf[0], pf[1]);
    f16x8 bIn1 = cvt_f16x8(pf[2], pf[3]);
    mS = pm;
    const int ridcur = rid;
    issue_gather();  // gather for next tile (ids already in idreg)
    char* slot = smXw + (par << 11);
#pragma unroll
    for (int nt = 0; nt < 4; ++nt) {
      f32x4 c = {0.f, 0.f, 0.f, 0.f};
      c = __builtin_amdgcn_mfma_f32_16x16x32_f16(aW[nt][0], bIn0, c, 0, 0, 0);
      c = __builtin_amdgcn_mfma_f32_16x16x32_f16(aW[nt][1], bIn1, c, 0, 0, 0);
      const float4 b1q = *(const float4*)(smem + OFF_B1 + nt * 64 + quad * 16);
      const float* b1p = (const float*)&b1q;
      const float4 r1q = *(const float4*)(sR1 + ridcur * 68 + nt * 16 + quad * 4);
      const float* r1p = (const float*)&r1q;
      f16x4 hv;
#pragma unroll
      for (int rg = 0; rg < 4; ++rg)
        hv[rg] = (_Float16)fmaxf(c[rg] + b1p[rg] + r1p[rg], 0.f);
      *(f16x4*)(slot + mrow * 128 +
                (((nt * 2 + (quad >> 1)) ^ (mrow & 7)) << 4) +
                ((quad & 1) << 3)) = hv;
    }
  };

  // stage2(t): H read -> d-path -> softmax -> c-path -> pnum; flush at group end
  auto stage2 = [&](const int idx, const int par, const float mS)
      __attribute__((always_inline)) {
    const int gq = isS ? (idx * 11) >> 5 : (idx >> 3);
    const int tt = idx - gq * tpg;
    const int g = wave + 4 * gq;
    if (tt == 0) {
#pragma unroll
      for (int nt = 0; nt < 4; ++nt) {
        vv[nt] = sV[g * 64 + nt * 16 + mrow];
        pnum[nt] = 0.f;
      }
      pden = 0.f;
    }
    char* slot = smXw + (par << 11);
    f16x8 a2[2];
#pragma unroll
    for (int ks = 0; ks < 2; ++ks)
      a2[ks] = *(const f16x8*)(slot + mrow * 128 +
                               (((ks * 4 + quad) ^ (mrow & 7)) << 4));
    float mk[4];
#pragma unroll
    for (int rg = 0; rg < 4; ++rg) mk[rg] = __shfl(mS, quad * 4 + rg);
    float tl[4] = {0.f, 0.f, 0.f, 0.f};
#pragma unroll
    for (int nt = 0; nt < 4; ++nt) {
      f32x4 d = {0.f, 0.f, 0.f, 0.f};
#pragma unroll
      for (int ks = 0; ks < 2; ++ks) {
        const f16x8 bM = *(const f16x8*)(smem + OFF_M2T + (nt * 16 + mrow) * 128 +
                                         (((ks * 4 + quad) ^ (mrow & 7)) << 4));
        d = __builtin_amdgcn_mfma_f32_16x16x32_f16(a2[ks], bM, d, 0, 0, 0);
      }
#pragma unroll
      for (int rg = 0; rg < 4; ++rg) {
        const float hh = fmaxf(d[rg] + cstv[nt] + mk[rg] * vv[nt], 0.f);
        tl[rg] = fmaf(hh, aw2v[nt], tl[rg]);
      }
    }
    float e[4];
#pragma unroll
    for (int rg = 0; rg < 4; ++rg) {
      float t = tl[rg];
      t += __shfl_xor(t, 1); t += __shfl_xor(t, 2);
      t += __shfl_xor(t, 4); t += __shfl_xor(t, 8);
      e[rg] = __expf(t + ab2) * mk[rg];
      pden += e[rg];
    }
#pragma unroll
    for (int nt = 0; nt < 4; ++nt) {
      f32x4 c = {0.f, 0.f, 0.f, 0.f};
#pragma unroll
      for (int ks = 0; ks < 2; ++ks) {
        const f16x8 bW = *(const f16x8*)(smem + OFF_W2T + (nt * 16 + mrow) * 128 +
                                         (((ks * 4 + quad) ^ (mrow & 7)) << 4));
        c = __builtin_amdgcn_mfma_f32_16x16x32_f16(a2[ks], bW, c, 0, 0, 0);
      }
      pnum[nt] = fmaf(e[0], c[0], pnum[nt]);
      pnum[nt] = fmaf(e[1], c[1], pnum[nt]);
      pnum[nt] = fmaf(e[2], c[2], pnum[nt]);
      pnum[nt] = fmaf(e[3], c[3], pnum[nt]);
    }
    if (tt == tpg - 1) {
      // ---- group flush (wave-local): quad-reduce + agg matvec + store ----
      float* csW = (float*)slot;  // tile's own (already-read) H half
      float dsum = pden;
      dsum += __shfl_xor(dsum, 16); dsum += __shfl_xor(dsum, 32);
      const float rd = 1.f / (dsum + EPSV);
#pragma unroll
      for (int nt = 0; nt < 4; ++nt) {
        float s = pnum[nt];
        s += __shfl_xor(s, 16); s += __shfl_xor(s, 32);
        if (quad == 0) csW[nt * 16 + mrow] = (s + b2v[nt] * dsum) * rd;
      }
      float acc = agg_b[lane];
#pragma unroll 8
      for (int k = 0; k < 64; ++k) acc = fmaf(csW[k], agg_W[k * 64 + lane], acc);
      out[(size_t)(gbase + g) * 64 + lane] = fmaxf(acc, 0.f);
    }
  };

  float mA, mB;
  load_ids(2);          // idreg for tile 1's gather was used; prep tile 2
  // NOTE: sequencing of load_ids/issue_gather: stage1 consumes pf (tile t),
  // then issues gather from idreg (tile t+1); we must load_ids(t+2) after.
  stage1(0, mA);        // consumes gather(0); issues gather(1) from idreg=ids(1)... 
  load_ids(3);          // (ids for tile 2 was loaded above BEFORE stage1 -> wrong slot)
  // Correction: the two load_ids calls above establish the invariant
  // "idreg = ids(t+1) when stage1(t) runs". stage1(0) needed idreg=ids(1)
  // (loaded in the prologue), so the first load_ids(2) above was premature;
  // it is overwritten harmlessly by load_ids(3)? NO — fix by ordering:
  // prologue loaded ids(1); we must NOT clobber before stage1(0).
  // (See corrected sequence below — this comment documents the invariant.)
  for (int idx = 0; idx < nIdx; idx += 2) {
    stage1(1, mB);      // tile idx+1: consumes gather(idx+1), issues gather(idx+2)
    load_ids(idx + 3);  // ids for tile idx+3
    stage2(idx, 0, mA);
    if (idx + 2 < nIdx) {
      stage1(0, mA);    // tile idx+2: consumes gather(idx+2), issues gather(idx+3)
      load_ids(idx + 4);
    }
    stage2(idx + 1, 1, mB);
  }
}

// ---------------- stage2 LDS layout (bytes) ----------------
#define S2_W1T 0       // 17408: attu_W1^T f16 [n][k], pitch 272 (bank-rotated)
#define S2_X   17408   // 8704:  2 waves x 16 rows x 272B
#define S2_E   26112   // 128:   2 x 16 f32
#define S2_MSK 26240   // 128:   2 x 16 f32
#define S2_HB  26368   // 1536:  2 x 192 f32 (concat/hidden ping-pong)
#define S2_SZ  27904

// ---------------------------------------------------------------------------
// Kernel 2: beta attention (MFMA) + h_iS + final 3-layer MLP.
// 256 blocks x 128 thr; wave w handles b = blockIdx*2 + w autonomously.
// ---------------------------------------------------------------------------
__global__ __launch_bounds__(128, 2) void stage2_kernel(
    const int* __restrict__ u_user_pad, const float* __restrict__ user_table,
    const float* __restrict__ hoI, const float* __restrict__ hiI,
    const float* __restrict__ attu_W1, const float* __restrict__ attu_b1,
    const float* __restrict__ attu_W2, const float* __restrict__ attu_b2,
    const float* __restrict__ aggn_W, const float* __restrict__ aggn_b,
    const float* __restrict__ cm_W1, const float* __restrict__ cm_b1,
    const float* __restrict__ cm_W2, const float* __restrict__ cm_b2,
    const float* __restrict__ cm_W3, const float* __restrict__ cm_b3,
    float* __restrict__ out) {
  __shared__ __align__(16) char smem[S2_SZ];
  const int tid = threadIdx.x;
  const int wave = tid >> 6, lane = tid & 63;
  const int quad = lane >> 4, mrow = lane & 15;
  const int b = (int)blockIdx.x * 2 + wave;

  char* sW1 = smem + S2_W1T;
  char* sXw = smem + S2_X + wave * 4352;
  float* sE = (float*)(smem + S2_E) + wave * 16;
  float* sM = (float*)(smem + S2_MSK) + wave * 16;
  float* sB = (float*)(smem + S2_HB) + wave * 192;

  for (int o = tid; o < 2048; o += 128) {
    const int k = o >> 4, fb = o & 15;
    const float4 v = ((const float4*)(attu_W1 + k * 64))[fb];
    const float* vp = (const float*)&v;
#pragma unroll
    for (int c = 0; c < 4; ++c) {
      const int n = fb * 4 + c;
      *(_Float16*)(sW1 + n * 272 + ((k >> 3) << 4) + ((k & 7) << 1)) = (_Float16)vp[c];
    }
  }
  float b1v[4], w2v[4];
#pragma unroll
  for (int nt = 0; nt < 4; ++nt) {
    b1v[nt] = attu_b1[nt * 16 + mrow];
    w2v[nt] = attu_W2[nt * 16 + mrow];
  }
  const float b2s = attu_b2[0];

  float4 pa[4], pb[4];
  float msk[4];
  auto pf = [&](int tt) __attribute__((always_inline)) {
#pragma unroll
    for (int k = 0; k < 4; ++k) {
      const int u = lane + (k << 6);
      const int r = u >> 4, bb = u & 15;
      const int q = tt * 16 + r;
      const int qc = q < 40 ? q : 39;
      int uid = 0;
      float m = 0.f;
      if (q < 40) {
        uid = u_user_pad[b * 40 + q];
        m = uid > 0 ? 1.f : 0.f;
      }
      msk[k] = m;
      const float* src = (bb < 8)
                             ? hoI + ((size_t)b * 40 + qc) * 64 + bb * 8
                             : user_table + (size_t)uid * 64 + (bb - 8) * 8;
      pa[k] = ((const float4*)src)[0];
      pb[k] = ((const float4*)src)[1];
    }
  };
  pf(0);
  __syncthreads();  // W1T ready

  float numer = 0.f, pden = 0.f;
  for (int tt = 0; tt < 3; ++tt) {
#pragma unroll
    for (int k = 0; k < 4; ++k) {
      const int u = lane + (k << 6);
      const int r = u >> 4, bb = u & 15;
      *(f16x8*)(sXw + r * 272 + (bb << 4)) = cvt_f16x8(pa[k], pb[k]);
      if (bb == 0) sM[r] = msk[k];
    }
    if (tt < 2) pf(tt + 1);
    f16x8 a[4];
#pragma unroll
    for (int ks = 0; ks < 4; ++ks)
      a[ks] = *(const f16x8*)(sXw + mrow * 272 + ((ks * 4 + quad) << 4));
    float mk[4];
#pragma unroll
    for (int rg = 0; rg < 4; ++rg) mk[rg] = sM[quad * 4 + rg];
    float tl[4] = {0.f, 0.f, 0.f, 0.f};
#pragma unroll
    for (int nt = 0; nt < 4; ++nt) {
      f32x4 d = {0.f, 0.f, 0.f, 0.f};
      const int n = nt * 16 + mrow;
#pragma unroll
      for (int ks = 0; ks < 4; ++ks) {
        const f16x8 bW = *(const f16x8*)(sW1 + n * 272 + ((ks * 4 + quad) << 4));
        d = __builtin_amdgcn_mfma_f32_16x16x32_f16(a[ks], bW, d, 0, 0, 0);
      }
#pragma unroll
      for (int rg = 0; rg < 4; ++rg) {
        const float h = fmaxf(d[rg] + b1v[nt], 0.f);
        tl[rg] = fmaf(h, w2v[nt], tl[rg]);
      }
    }
    float e[4];
#pragma unroll
    for (int rg = 0; rg < 4; ++rg) {
      float t = tl[rg];
      t += __shfl_xor(t, 1); t += __shfl_xor(t, 2);
      t += __shfl_xor(t, 4); t += __shfl_xor(t, 8);
      e[rg] = __expf(t + b2s) * mk[rg];
      pden += e[rg];
    }
    if (mrow == 0) {
#pragma unroll
      for (int rg = 0; rg < 4; ++rg) sE[quad * 4 + rg] = e[rg];
    }
#pragma unroll 4
    for (int r = 0; r < 16; ++r) {
      const float er = sE[r];
      const float xv = (float)*(const _Float16*)(sXw + r * 272 + ((lane >> 3) << 4) +
                                                 ((lane & 7) << 1));
      numer = fmaf(er, xv, numer);
    }
  }
  pden += __shfl_xor(pden, 16);
  pden += __shfl_xor(pden, 32);
  const float hagg = numer / (pden + EPSV);

  sB[128 + lane] = hagg;
  sB[lane] = hiI[(size_t)b * 64 + lane];
  float acc = aggn_b[lane];
#pragma unroll 8
  for (int k = 0; k < 64; ++k) acc = fmaf(sB[128 + k], aggn_W[k * 64 + lane], acc);
  sB[64 + lane] = fmaxf(acc, 0.f);
  float c1 = cm_b1[lane];
#pragma unroll 8
  for (int k = 0; k < 128; ++k) c1 = fmaf(sB[k], cm_W1[k * 64 + lane], c1);
  sB[128 + lane] = fmaxf(c1, 0.f);
  float c2 = cm_b2[lane];
#pragma unroll 8
  for (int k = 0; k < 64; ++k) c2 = fmaf(sB[128 + k], cm_W2[k * 64 + lane], c2);
  sB[lane] = fmaxf(c2, 0.f);
  float c3 = cm_b3[lane];
#pragma unroll 8
  for (int k = 0; k < 64; ++k) c3 = fmaf(sB[k], cm_W3[k * 64 + lane], c3);
  out[(size_t)b * 64 + lane] = fmaxf(c3, 0.f);
}

extern "C" void kernel_launch(void* const* d_in, const int* in_sizes, int n_in,
                              void* d_out, int out_size, void* d_ws, size_t ws_size,
                              hipStream_t stream) {
  const int* uids = (const int*)d_in[0];
  const int* u_item_pad = (const int*)d_in[1];
  const int* u_user_pad = (const int*)d_in[2];
  const int* u_user_item_pad = (const int*)d_in[3];
  const float* user_table = (const float*)d_in[4];
  const float* item_table = (const float*)d_in[5];
  const float* rate_table = (const float*)d_in[6];
  const float* gv_W1 = (const float*)d_in[7];
  const float* gv_b1 = (const float*)d_in[8];
  const float* gv_W2 = (const float*)d_in[9];
  const float* gv_b2 = (const float*)d_in[10];
  const float* atti_W1 = (const float*)d_in[11];
  const float* atti_b1 = (const float*)d_in[12];
  const float* atti_W2 = (const float*)d_in[13];
  const float* atti_b2 = (const float*)d_in[14];
  const float* agg_W = (const float*)d_in[15];
  const float* agg_b = (const float*)d_in[16];
  const float* attu_W1 = (const float*)d_in[17];
  const float* attu_b1 = (const float*)d_in[18];
  const float* attu_W2 = (const float*)d_in[19];
  const float* attu_b2 = (const float*)d_in[20];
  const float* aggn_W = (const float*)d_in[21];
  const float* aggn_b = (const float*)d_in[22];
  const float* cm_W1 = (const float*)d_in[23];
  const float* cm_b1 = (const float*)d_in[24];
  const float* cm_W2 = (const float*)d_in[25];
  const float* cm_b2 = (const float*)d_in[26];
  const float* cm_W3 = (const float*)d_in[27];
  const float* cm_b3 = (const float*)d_in[28];
  float* out = (float*)d_out;

  float* hoI = (float*)d_ws;                 // 512*40*64 floats
  float* hiI = hoI + (size_t)512 * 40 * 64;  // 512*64 floats

  // Merged I (128 blocks x 4 groups, dispatched first) + S (1280 x 16).
  agg_kernel<<<128 + 1280, 256, 0, stream>>>(
      128, u_user_item_pad, u_user_pad, u_item_pad, uids,
      user_table, item_table, rate_table,
      gv_W1, gv_b1, gv_W2, gv_b2,
      atti_W1, atti_b1, atti_W2, atti_b2,
      agg_W, agg_b, hoI, hiI);
  // Beta attention + h_iS + final MLP (wave-autonomous MFMA).
  stage2_kernel<<<256, 128, 0, stream>>>(u_user_pad, user_table, hoI, hiI,
                                         attu_W1, attu_b1, attu_W2, attu_b2,
                                         aggn_W, aggn_b,
                                         cm_W1, cm_b1, cm_W2, cm_b2, cm_W3, cm_b3,
                                         out);
}

// Round 12
// 266.032 us; speedup vs baseline: 1.0030x; 1.0030x over previous
//
#include <hip/hip_runtime.h>
#include <math.h>

#define EPSV 1e-10f

typedef _Float16 f16x8 __attribute__((ext_vector_type(8)));
typedef _Float16 f16x4 __attribute__((ext_vector_type(4)));
typedef float f32x4 __attribute__((ext_vector_type(4)));

// ---------------- agg LDS layout (bytes), R18 (32KB, 5 blocks/CU-capable) ----------------
// A (0..8192):      W1T f16 [64][128] swz (P2a-B5) -> 4 wave-private H slots
//                   (wave*2048, 16 rows x 128B) in main loop; csW at flush.
// B (8192..16384):  W2T[n2][h] f16 swz (P2a -> end)
// C (16384..24576): M2T[n3][h] f16 swz (P2b -> end)
// AU f32 [64][64] = 16KB overlays B+C during P0/P1 (dead before W2T staged).
// D (24576..28672): uS f32 16x64 (P0/P1); then cstP(1K) + sR1 f32 [6][68]
//                   (25856.., = R1 + b1 folded, live in main loop)
// E (28672..32768): sV[g][n], g < 16
#define OFF_W1T  0
#define OFF_AU   8192
#define OFF_W2T  8192
#define OFF_M2T  16384
#define OFF_U    24576
#define OFF_R1   25856
#define OFF_V    28672
#define SMEM_SZ  32768

__device__ __forceinline__ f16x8 cvt_f16x8(const float4 a, const float4 b) {
  f16x8 h;
  h[0] = (_Float16)a.x; h[1] = (_Float16)a.y; h[2] = (_Float16)a.z; h[3] = (_Float16)a.w;
  h[4] = (_Float16)b.x; h[5] = (_Float16)b.y; h[6] = (_Float16)b.z; h[7] = (_Float16)b.w;
  return h;
}

// DPP quad_perm adds: exact xor-1 / xor-2 cross-lane sums at VALU speed
// (replaces ~120cy ds_bpermute shfl with ~4cy DPP; quad_perm[1,0,3,2]=0xB1,
//  quad_perm[2,3,0,1]=0x4E — both stay within 4-lane quads).
__device__ __forceinline__ float qpx1_add(float x) {
  return x + __int_as_float(__builtin_amdgcn_update_dpp(
                 0, __float_as_int(x), 0xB1, 0xF, 0xF, false));
}
__device__ __forceinline__ float qpx2_add(float x) {
  return x + __int_as_float(__builtin_amdgcn_update_dpp(
                 0, __float_as_int(x), 0x4E, 0xF, 0xF, false));
}

// ---------------------------------------------------------------------------
// Fused item-aggregation. I-blocks FIRST [0,nIblk): 4 groups (P=100, 1/wave);
// S-blocks after: 16 groups (P=40, 4/wave). 256 thr = 4 waves.
// R18: cut the per-tile CROSS-LANE latency chain (R17 exonerated the H
// round-trip; shfl/bpermute ~120cy each made mk + 4-deep softmax reduce
// ~600cy of the ~1100cy tile):
// (a) mk via __ballot bit-extract (VALU) instead of __shfl    [-120cy]
// (b) softmax reduce xor1/xor2 via DPP quad_perm adds (VALU)  [-240cy]
// (c) gv_b1 folded into sR1 (= R1 + b1): -4 LDS reads, -16 adds, exact.
// Body otherwise = R16 (proven correct, 266us). Tripwires: FETCH ~101MB /
// WRITE ~5.2MB / VGPR ~76-84.
// ---------------------------------------------------------------------------
__global__ __launch_bounds__(256, 3) void agg_kernel(
    const int nIblk,
    const int* __restrict__ idsS, const int* __restrict__ uidS,
    const int* __restrict__ idsI, const int* __restrict__ uidI,
    const float* __restrict__ user_table, const float* __restrict__ item_table,
    const float* __restrict__ rate_table,
    const float* __restrict__ gv_W1, const float* __restrict__ gv_b1,
    const float* __restrict__ gv_W2, const float* __restrict__ gv_b2,
    const float* __restrict__ atti_W1, const float* __restrict__ atti_b1,
    const float* __restrict__ atti_W2, const float* __restrict__ atti_b2,
    const float* __restrict__ agg_W, const float* __restrict__ agg_b,
    float* __restrict__ outS, float* __restrict__ outI) {
  __shared__ __align__(16) char smem[SMEM_SZ];
  const int tid = threadIdx.x;
  const int wave = tid >> 6, lane = tid & 63;
  const int quad = lane >> 4, mrow = lane & 15;

  const bool isS = (int)blockIdx.x >= nIblk;
  const int NG = isS ? 16 : 4;
  const int P = isS ? 40 : 100;
  const int nGrp = isS ? 4 : 1;  // groups per wave
  const int tpg = isS ? 3 : 8;   // 16-row tiles per group
  const int nIdx = nGrp * tpg;   // 12 or 8
  const int* __restrict__ ids = isS ? idsS : idsI;
  const int* __restrict__ uidp = isS ? uidS : uidI;
  float* __restrict__ out = isS ? outS : outI;
  const int gbase = isS ? ((int)blockIdx.x - nIblk) * 16 : (int)blockIdx.x * 4;

  float* sV = (float*)(smem + OFF_V);
  char* smXw = smem + OFF_W1T + wave * 2048;  // wave-private H slot (post-B5)
  float* csW = (float*)smXw;                  // epilogue c vector (H dead then)

  // ---- P0: uS (region D) + AU = AW1u^T f32 (overlay on B+C, f4-swizzled) ----
  {
    float* uS = (float*)(smem + OFF_U);
    float* AU = (float*)(smem + OFF_AU);
    for (int t = tid; t < NG * 64; t += 256) {
      const int g = t >> 6, f = t & 63;
      uS[t] = user_table[(size_t)uidp[gbase + g] * 64 + f];
    }
    for (int o = tid; o < 1024; o += 256) {  // AU[j][k] = atti_W1[64+k][j]
      const int k = o >> 4, fb = o & 15;
      const float4 v = ((const float4*)(atti_W1 + (64 + k) * 64))[fb];
      const float* vp = (const float*)&v;
#pragma unroll
      for (int c = 0; c < 4; ++c) {
        const int j = fb * 4 + c;
        AU[j * 64 + (((k >> 2) ^ (j & 15)) << 2) + (k & 3)] = vp[c];
      }
    }
  }
  __syncthreads();
  // ---- P1: v[g][j] = u[g] . AW1u[:,j] ----
  {
    const float4* u4 = (const float4*)(smem + OFF_U);
    const float4* a4 = (const float4*)(smem + OFF_AU);
    for (int t = tid; t < NG * 64; t += 256) {
      const int g = t >> 6, j = t & 63;
      float s = 0.f;
#pragma unroll 4
      for (int kb = 0; kb < 16; ++kb) {
        const float4 uu = u4[g * 16 + kb];
        const float4 aa = a4[j * 16 + (kb ^ (j & 15))];
        s += uu.x * aa.x + uu.y * aa.y + uu.z * aa.z + uu.w * aa.w;
      }
      sV[t] = s;
    }
  }
  __syncthreads();  // AU dead beyond this point (B/C regions reusable)
  // ---- P2a: W1T(item)/W2T f16 staging + sR1 (= R1 + b1) + cst partials ----
  {
    for (int o = tid; o < 1024; o += 256) {  // W1T[n][k], k in 0..63 (item)
      const int k = o >> 4, fb = o & 15;
      const float4 v = ((const float4*)(gv_W1 + k * 64))[fb];
      const float* vp = (const float*)&v;
#pragma unroll
      for (int c = 0; c < 4; ++c) {
        const int n = fb * 4 + c;
        *(_Float16*)(smem + OFF_W1T + n * 128 + ((((k >> 3) ^ (n & 7))) << 4) +
                     ((k & 7) << 1)) = (_Float16)vp[c];
      }
    }
    for (int o = tid; o < 1024; o += 256) {  // W2T[n2][h]
      const int h = o >> 4, fb = o & 15;
      const float4 v = ((const float4*)(gv_W2 + h * 64))[fb];
      const float* vp = (const float*)&v;
#pragma unroll
      for (int c = 0; c < 4; ++c) {
        const int n = fb * 4 + c;
        *(_Float16*)(smem + OFF_W2T + n * 128 + ((((h >> 3) ^ (n & 7))) << 4) +
                     ((h & 7) << 1)) = (_Float16)vp[c];
      }
    }
    // sR1 f32: R1[r][n] = rate_r . W1[64:,n] + b1[n] (b1 folded; exact),
    // pitch 68 floats (bank-spread)
    {
      float* sR1 = (float*)(smem + OFF_R1);
      for (int o = tid; o < 384; o += 256) {
        const int r = o >> 6, n = o & 63;
        float s = gv_b1[n];
#pragma unroll 8
        for (int k = 0; k < 64; ++k)
          s = fmaf(rate_table[r * 64 + k], gv_W1[(64 + k) * 64 + n], s);
        sR1[r * 68 + n] = s;
      }
    }
    float* sCstP = (float*)(smem + OFF_U);  // uS dead after P1
    const int n = tid & 63, jh = tid >> 6;
    float p = 0.f;
#pragma unroll 4
    for (int jj = 0; jj < 16; ++jj) {
      const int j = jh * 16 + jj;
      p = fmaf(gv_b2[j], atti_W1[j * 64 + n], p);
    }
    sCstP[jh * 64 + n] = p;
  }
  // per-lane constant preloads (global, L2-hot)
  float b2v[4], aw2v[4];
#pragma unroll
  for (int nt = 0; nt < 4; ++nt) {
    b2v[nt] = gv_b2[nt * 16 + mrow];
    aw2v[nt] = atti_W2[nt * 16 + mrow];
  }
  const float ab2 = atti_b2[0];

  // ---- single-buffer split prefetch (1 tile lookahead) ----
  const int nIdxM1 = nIdx - 1;
  int2 idreg;
  float4 pf[4];
  float pm;
  int rid;
  auto load_ids = [&](int idx) __attribute__((always_inline)) {
    const int ic = idx < nIdxM1 ? idx : nIdxM1;  // clamp (tail prefetch harmless)
    const int gq = isS ? (ic * 11) >> 5 : (ic >> 3);  // /3 or /8, ic<=11
    const int tt = ic - gq * tpg;
    const int it = tt * 16 + mrow;
    int2 pr = make_int2(0, 0);
    if (it < P) {
      const int g2 = gbase + wave + 4 * gq;
      pr = ((const int2*)ids)[(size_t)g2 * P + it];
    }
    idreg = pr;
  };
  auto issue_gather = [&]() __attribute__((always_inline)) {
    const int iid = idreg.x;
    rid = idreg.y;
    pm = iid > 0 ? 1.f : 0.f;
    const float* ib = item_table + (size_t)iid * 64 + quad * 8;
    pf[0] = ((const float4*)ib)[0];
    pf[1] = ((const float4*)ib)[1];
    pf[2] = ((const float4*)(ib + 32))[0];
    pf[3] = ((const float4*)(ib + 32))[1];
  };
  load_ids(0); issue_gather();
  load_ids(1);      // in flight across P2b
  __syncthreads();  // B3: W1T/W2T/cstP/sR1 ready
  // ---- P2b: M2T via MFMA (A,B from L2-hot global) + cstv to registers ----
  float cstv[4];
  {
    f16x8 aM[2];
#pragma unroll
    for (int ks = 0; ks < 2; ++ks) {
      f16x8 t;
#pragma unroll
      for (int j = 0; j < 8; ++j)
        t[j] = (_Float16)atti_W1[(ks * 32 + quad * 8 + j) * 64 + (wave * 16 + mrow)];
      aM[ks] = t;
    }
#pragma unroll
    for (int ht = 0; ht < 4; ++ht) {
      f32x4 c = {0.f, 0.f, 0.f, 0.f};
#pragma unroll
      for (int ks = 0; ks < 2; ++ks) {
        const float* s = gv_W2 + (ht * 16 + mrow) * 64 + ks * 32 + quad * 8;
        f16x8 b;
#pragma unroll
        for (int j = 0; j < 8; ++j) b[j] = (_Float16)s[j];
        c = __builtin_amdgcn_mfma_f32_16x16x32_f16(aM[ks], b, c, 0, 0, 0);
      }
      const int h = ht * 16 + mrow;
#pragma unroll
      for (int rg = 0; rg < 4; ++rg) {
        const int n3 = wave * 16 + quad * 4 + rg;
        *(_Float16*)(smem + OFF_M2T + n3 * 128 + ((((h >> 3) ^ (n3 & 7))) << 4) +
                     ((h & 7) << 1)) = (_Float16)c[rg];
      }
    }
    const float* sCstP = (const float*)(smem + OFF_U);
#pragma unroll
    for (int nt = 0; nt < 4; ++nt) {
      const int n = nt * 16 + mrow;
      cstv[nt] = atti_b1[n] + sCstP[n] + sCstP[64 + n] + sCstP[128 + n] +
                 sCstP[192 + n];
    }
  }
  __syncthreads();  // B4: M2T ready

  // ---- hoist W1 A-frags (item k-halves only) into registers ----
  f16x8 aW[4][2];
#pragma unroll
  for (int nt = 0; nt < 4; ++nt) {
#pragma unroll
    for (int ks = 0; ks < 2; ++ks)
      aW[nt][ks] = *(const f16x8*)(smem + OFF_W1T + (nt * 16 + mrow) * 128 +
                                   (((ks * 4 + quad) ^ (mrow & 7)) << 4));
  }
  __syncthreads();  // B5: hoist done; region A becomes per-wave H slots

  // =================== barrier-free main loop ===================
  const float* sR1 = (const float*)(smem + OFF_R1);
  float vv[4], pnum[4], pden = 0.f;
  for (int idx = 0; idx < nIdx; ++idx) {
    const int gq = isS ? (idx * 11) >> 5 : (idx >> 3);
    const int tt = idx - gq * tpg;
    const int g = wave + 4 * gq;
    if (tt == 0) {
#pragma unroll
      for (int nt = 0; nt < 4; ++nt) {
        vv[nt] = sV[g * 64 + nt * 16 + mrow];
        pnum[nt] = 0.f;
      }
      pden = 0.f;
    }
    // In B-frags straight from prefetched registers (no LDS)
    f16x8 bIn0 = cvt_f16x8(pf[0], pf[1]);
    f16x8 bIn1 = cvt_f16x8(pf[2], pf[3]);
    // tile mask as a ballot bitmask: bit l = lane l's row valid; row r's
    // mask sits at bit r (quad 0). VALU extract replaces a ~120cy shfl.
    const unsigned long long mball = __ballot(pm > 0.5f);
    const int ridcur = rid;
    issue_gather();      // gather for tile idx+1 (ids in idreg)
    load_ids(idx + 2);   // ids for tile idx+2 -> idreg
    // ---- layer1 (transposed): H^T -> b64 writes to wave-private slot ----
    // rate+b1 contribution added exactly: + sR1[rid(item=mrow)][n] (f32 LDS)
#pragma unroll
    for (int nt = 0; nt < 4; ++nt) {
      f32x4 c = {0.f, 0.f, 0.f, 0.f};
      c = __builtin_amdgcn_mfma_f32_16x16x32_f16(aW[nt][0], bIn0, c, 0, 0, 0);
      c = __builtin_amdgcn_mfma_f32_16x16x32_f16(aW[nt][1], bIn1, c, 0, 0, 0);
      const float4 r1q = *(const float4*)(sR1 + ridcur * 68 + nt * 16 + quad * 4);
      const float* r1p = (const float*)&r1q;
      f16x4 hv;
#pragma unroll
      for (int rg = 0; rg < 4; ++rg)
        hv[rg] = (_Float16)fmaxf(c[rg] + r1p[rg], 0.f);
      *(f16x4*)(smXw + mrow * 128 +
                (((nt * 2 + (quad >> 1)) ^ (mrow & 7)) << 4) +
                ((quad & 1) << 3)) = hv;
    }
    // ---- H A-frags for layer2 + attention ----
    f16x8 a2[2];
#pragma unroll
    for (int ks = 0; ks < 2; ++ks)
      a2[ks] = *(const f16x8*)(smXw + mrow * 128 +
                               (((ks * 4 + quad) ^ (mrow & 7)) << 4));
    float mk[4];
#pragma unroll
    for (int rg = 0; rg < 4; ++rg)
      mk[rg] = (float)((mball >> (quad * 4 + rg)) & 1ULL);
    // d-path first (attention logits); c-path MFMAs are e-independent
    float tl[4] = {0.f, 0.f, 0.f, 0.f};
#pragma unroll
    for (int nt = 0; nt < 4; ++nt) {
      f32x4 d = {0.f, 0.f, 0.f, 0.f};
#pragma unroll
      for (int ks = 0; ks < 2; ++ks) {
        const f16x8 bM = *(const f16x8*)(smem + OFF_M2T + (nt * 16 + mrow) * 128 +
                                         (((ks * 4 + quad) ^ (mrow & 7)) << 4));
        d = __builtin_amdgcn_mfma_f32_16x16x32_f16(a2[ks], bM, d, 0, 0, 0);
      }
#pragma unroll
      for (int rg = 0; rg < 4; ++rg) {
        const float hh = fmaxf(d[rg] + cstv[nt] + mk[rg] * vv[nt], 0.f);
        tl[rg] = fmaf(hh, aw2v[nt], tl[rg]);
      }
    }
    float e[4];
#pragma unroll
    for (int rg = 0; rg < 4; ++rg) {
      float t = tl[rg];
      t = qpx1_add(t);          // xor-1 via DPP quad_perm (VALU)
      t = qpx2_add(t);          // xor-2 via DPP quad_perm (VALU)
      t += __shfl_xor(t, 4); t += __shfl_xor(t, 8);
      e[rg] = __expf(t + ab2) * mk[rg];
      pden += e[rg];
    }
    // c-path (x2) consumed straight into pnum (b2 folded at flush)
#pragma unroll
    for (int nt = 0; nt < 4; ++nt) {
      f32x4 c = {0.f, 0.f, 0.f, 0.f};
#pragma unroll
      for (int ks = 0; ks < 2; ++ks) {
        const f16x8 bW = *(const f16x8*)(smem + OFF_W2T + (nt * 16 + mrow) * 128 +
                                         (((ks * 4 + quad) ^ (mrow & 7)) << 4));
        c = __builtin_amdgcn_mfma_f32_16x16x32_f16(a2[ks], bW, c, 0, 0, 0);
      }
      pnum[nt] = fmaf(e[0], c[0], pnum[nt]);
      pnum[nt] = fmaf(e[1], c[1], pnum[nt]);
      pnum[nt] = fmaf(e[2], c[2], pnum[nt]);
      pnum[nt] = fmaf(e[3], c[3], pnum[nt]);
    }
    if (tt == tpg - 1) {
      // ---- group flush (wave-local): quad-reduce + agg matvec + store ----
      float dsum = pden;
      dsum += __shfl_xor(dsum, 16); dsum += __shfl_xor(dsum, 32);
      const float rd = 1.f / (dsum + EPSV);
#pragma unroll
      for (int nt = 0; nt < 4; ++nt) {
        float s = pnum[nt];
        s += __shfl_xor(s, 16); s += __shfl_xor(s, 32);
        if (quad == 0) csW[nt * 16 + mrow] = (s + b2v[nt] * dsum) * rd;
      }
      float acc = agg_b[lane];
#pragma unroll 8
      for (int k = 0; k < 64; ++k) acc = fmaf(csW[k], agg_W[k * 64 + lane], acc);
      out[(size_t)(gbase + g) * 64 + lane] = fmaxf(acc, 0.f);
    }
  }
}

// ---------------- stage2 LDS layout (bytes) ----------------
#define S2_W1T 0       // 17408: attu_W1^T f16 [n][k], pitch 272 (bank-rotated)
#define S2_X   17408   // 8704:  2 waves x 16 rows x 272B
#define S2_E   26112   // 128:   2 x 16 f32
#define S2_MSK 26240   // 128:   2 x 16 f32
#define S2_HB  26368   // 1536:  2 x 192 f32 (concat/hidden ping-pong)
#define S2_SZ  27904

// ---------------------------------------------------------------------------
// Kernel 2: beta attention (MFMA) + h_iS + final 3-layer MLP.
// 256 blocks x 128 thr; wave w handles b = blockIdx*2 + w autonomously.
// ---------------------------------------------------------------------------
__global__ __launch_bounds__(128, 2) void stage2_kernel(
    const int* __restrict__ u_user_pad, const float* __restrict__ user_table,
    const float* __restrict__ hoI, const float* __restrict__ hiI,
    const float* __restrict__ attu_W1, const float* __restrict__ attu_b1,
    const float* __restrict__ attu_W2, const float* __restrict__ attu_b2,
    const float* __restrict__ aggn_W, const float* __restrict__ aggn_b,
    const float* __restrict__ cm_W1, const float* __restrict__ cm_b1,
    const float* __restrict__ cm_W2, const float* __restrict__ cm_b2,
    const float* __restrict__ cm_W3, const float* __restrict__ cm_b3,
    float* __restrict__ out) {
  __shared__ __align__(16) char smem[S2_SZ];
  const int tid = threadIdx.x;
  const int wave = tid >> 6, lane = tid & 63;
  const int quad = lane >> 4, mrow = lane & 15;
  const int b = (int)blockIdx.x * 2 + wave;

  char* sW1 = smem + S2_W1T;
  char* sXw = smem + S2_X + wave * 4352;
  float* sE = (float*)(smem + S2_E) + wave * 16;
  float* sM = (float*)(smem + S2_MSK) + wave * 16;
  float* sB = (float*)(smem + S2_HB) + wave * 192;

  for (int o = tid; o < 2048; o += 128) {
    const int k = o >> 4, fb = o & 15;
    const float4 v = ((const float4*)(attu_W1 + k * 64))[fb];
    const float* vp = (const float*)&v;
#pragma unroll
    for (int c = 0; c < 4; ++c) {
      const int n = fb * 4 + c;
      *(_Float16*)(sW1 + n * 272 + ((k >> 3) << 4) + ((k & 7) << 1)) = (_Float16)vp[c];
    }
  }
  float b1v[4], w2v[4];
#pragma unroll
  for (int nt = 0; nt < 4; ++nt) {
    b1v[nt] = attu_b1[nt * 16 + mrow];
    w2v[nt] = attu_W2[nt * 16 + mrow];
  }
  const float b2s = attu_b2[0];

  float4 pa[4], pb[4];
  float msk[4];
  auto pf = [&](int tt) __attribute__((always_inline)) {
#pragma unroll
    for (int k = 0; k < 4; ++k) {
      const int u = lane + (k << 6);
      const int r = u >> 4, bb = u & 15;
      const int q = tt * 16 + r;
      const int qc = q < 40 ? q : 39;
      int uid = 0;
      float m = 0.f;
      if (q < 40) {
        uid = u_user_pad[b * 40 + q];
        m = uid > 0 ? 1.f : 0.f;
      }
      msk[k] = m;
      const float* src = (bb < 8)
                             ? hoI + ((size_t)b * 40 + qc) * 64 + bb * 8
                             : user_table + (size_t)uid * 64 + (bb - 8) * 8;
      pa[k] = ((const float4*)src)[0];
      pb[k] = ((const float4*)src)[1];
    }
  };
  pf(0);
  __syncthreads();  // W1T ready

  float numer = 0.f, pden = 0.f;
  for (int tt = 0; tt < 3; ++tt) {
#pragma unroll
    for (int k = 0; k < 4; ++k) {
      const int u = lane + (k << 6);
      const int r = u >> 4, bb = u & 15;
      *(f16x8*)(sXw + r * 272 + (bb << 4)) = cvt_f16x8(pa[k], pb[k]);
      if (bb == 0) sM[r] = msk[k];
    }
    if (tt < 2) pf(tt + 1);
    f16x8 a[4];
#pragma unroll
    for (int ks = 0; ks < 4; ++ks)
      a[ks] = *(const f16x8*)(sXw + mrow * 272 + ((ks * 4 + quad) << 4));
    float mk[4];
#pragma unroll
    for (int rg = 0; rg < 4; ++rg) mk[rg] = sM[quad * 4 + rg];
    float tl[4] = {0.f, 0.f, 0.f, 0.f};
#pragma unroll
    for (int nt = 0; nt < 4; ++nt) {
      f32x4 d = {0.f, 0.f, 0.f, 0.f};
      const int n = nt * 16 + mrow;
#pragma unroll
      for (int ks = 0; ks < 4; ++ks) {
        const f16x8 bW = *(const f16x8*)(sW1 + n * 272 + ((ks * 4 + quad) << 4));
        d = __builtin_amdgcn_mfma_f32_16x16x32_f16(a[ks], bW, d, 0, 0, 0);
      }
#pragma unroll
      for (int rg = 0; rg < 4; ++rg) {
        const float h = fmaxf(d[rg] + b1v[nt], 0.f);
        tl[rg] = fmaf(h, w2v[nt], tl[rg]);
      }
    }
    float e[4];
#pragma unroll
    for (int rg = 0; rg < 4; ++rg) {
      float t = tl[rg];
      t = qpx1_add(t);
      t = qpx2_add(t);
      t += __shfl_xor(t, 4); t += __shfl_xor(t, 8);
      e[rg] = __expf(t + b2s) * mk[rg];
      pden += e[rg];
    }
    if (mrow == 0) {
#pragma unroll
      for (int rg = 0; rg < 4; ++rg) sE[quad * 4 + rg] = e[rg];
    }
#pragma unroll 4
    for (int r = 0; r < 16; ++r) {
      const float er = sE[r];
      const float xv = (float)*(const _Float16*)(sXw + r * 272 + ((lane >> 3) << 4) +
                                                 ((lane & 7) << 1));
      numer = fmaf(er, xv, numer);
    }
  }
  pden += __shfl_xor(pden, 16);
  pden += __shfl_xor(pden, 32);
  const float hagg = numer / (pden + EPSV);

  sB[128 + lane] = hagg;
  sB[lane] = hiI[(size_t)b * 64 + lane];
  float acc = aggn_b[lane];
#pragma unroll 8
  for (int k = 0; k < 64; ++k) acc = fmaf(sB[128 + k], aggn_W[k * 64 + lane], acc);
  sB[64 + lane] = fmaxf(acc, 0.f);
  float c1 = cm_b1[lane];
#pragma unroll 8
  for (int k = 0; k < 128; ++k) c1 = fmaf(sB[k], cm_W1[k * 64 + lane], c1);
  sB[128 + lane] = fmaxf(c1, 0.f);
  float c2 = cm_b2[lane];
#pragma unroll 8
  for (int k = 0; k < 64; ++k) c2 = fmaf(sB[128 + k], cm_W2[k * 64 + lane], c2);
  sB[lane] = fmaxf(c2, 0.f);
  float c3 = cm_b3[lane];
#pragma unroll 8
  for (int k = 0; k < 64; ++k) c3 = fmaf(sB[k], cm_W3[k * 64 + lane], c3);
  out[(size_t)b * 64 + lane] = fmaxf(c3, 0.f);
}

extern "C" void kernel_launch(void* const* d_in, const int* in_sizes, int n_in,
                              void* d_out, int out_size, void* d_ws, size_t ws_size,
                              hipStream_t stream) {
  const int* uids = (const int*)d_in[0];
  const int* u_item_pad = (const int*)d_in[1];
  const int* u_user_pad = (const int*)d_in[2];
  const int* u_user_item_pad = (const int*)d_in[3];
  const float* user_table = (const float*)d_in[4];
  const float* item_table = (const float*)d_in[5];
  const float* rate_table = (const float*)d_in[6];
  const float* gv_W1 = (const float*)d_in[7];
  const float* gv_b1 = (const float*)d_in[8];
  const float* gv_W2 = (const float*)d_in[9];
  const float* gv_b2 = (const float*)d_in[10];
  const float* atti_W1 = (const float*)d_in[11];
  const float* atti_b1 = (const float*)d_in[12];
  const float* atti_W2 = (const float*)d_in[13];
  const float* atti_b2 = (const float*)d_in[14];
  const float* agg_W = (const float*)d_in[15];
  const float* agg_b = (const float*)d_in[16];
  const float* attu_W1 = (const float*)d_in[17];
  const float* attu_b1 = (const float*)d_in[18];
  const float* attu_W2 = (const float*)d_in[19];
  const float* attu_b2 = (const float*)d_in[20];
  const float* aggn_W = (const float*)d_in[21];
  const float* aggn_b = (const float*)d_in[22];
  const float* cm_W1 = (const float*)d_in[23];
  const float* cm_b1 = (const float*)d_in[24];
  const float* cm_W2 = (const float*)d_in[25];
  const float* cm_b2 = (const float*)d_in[26];
  const float* cm_W3 = (const float*)d_in[27];
  const float* cm_b3 = (const float*)d_in[28];
  float* out = (float*)d_out;

  float* hoI = (float*)d_ws;                 // 512*40*64 floats
  float* hiI = hoI + (size_t)512 * 40 * 64;  // 512*64 floats

  // Merged I (128 blocks x 4 groups, dispatched first) + S (1280 x 16).
  agg_kernel<<<128 + 1280, 256, 0, stream>>>(
      128, u_user_item_pad, u_user_pad, u_item_pad, uids,
      user_table, item_table, rate_table,
      gv_W1, gv_b1, gv_W2, gv_b2,
      atti_W1, atti_b1, atti_W2, atti_b2,
      agg_W, agg_b, hoI, hiI);
  // Beta attention + h_iS + final MLP (wave-autonomous MFMA).
  stage2_kernel<<<256, 128, 0, stream>>>(u_user_pad, user_table, hoI, hiI,
                                         attu_W1, attu_b1, attu_W2, attu_b2,
                                         aggn_W, aggn_b,
                                         cm_W1, cm_b1, cm_W2, cm_b2, cm_W3, cm_b3,
                                         out);
}